// Round 10
// baseline (399.372 us; speedup 1.0000x reference)
//
#include <hip/hip_runtime.h>
#include <hip/hip_bf16.h>

#define NN 3072
#define DM 256
#define NH 8
#define HDIM 32
#define NE 98304
#define DFF 1024
#define MAXDEG 512
#define NIT 192   // NN/16 i-tiles
#define NJT 48    // NN/64 j-tiles
#define JSPLIT 4

typedef short bf16x8 __attribute__((ext_vector_type(8)));
typedef float f32x4 __attribute__((ext_vector_type(4)));
typedef unsigned short u16;
typedef unsigned int u32;

#define MFMA16 __builtin_amdgcn_mfma_f32_16x16x32_bf16

__device__ __forceinline__ u16 f2bf(float f){
  u32 u = __builtin_bit_cast(u32, f);
  u32 r = (u + 0x7FFFu + ((u >> 16) & 1u)) >> 16;
  return (u16)r;
}
__device__ __forceinline__ u32 cvtpk(float lo, float hi){
  u32 r; asm("v_cvt_pk_bf16_f32 %0, %1, %2" : "=v"(r) : "v"(lo), "v"(hi)); return r;
}

// ---------------- degree + bucket count ----------------
__global__ void k_deg(const int* __restrict__ src, const int* __restrict__ dst,
                      int* __restrict__ deg_out, int* __restrict__ deg_in,
                      int* __restrict__ bcnt){
  int e = blockIdx.x * 256 + threadIdx.x;
  if (e < NE){
    int s = src[e], d = dst[e];
    atomicAdd(&deg_out[s], 1);
    atomicAdd(&deg_in[d], 1);
    atomicAdd(&bcnt[(s >> 4) * NJT + (d >> 6)], 1);
  }
}

// ---------------- exclusive scan of bcnt[9216] -> bptr[9217] ----------------
__global__ __launch_bounds__(1024)
void k_scan(const int* __restrict__ cnt, int* __restrict__ ptr){
  __shared__ int sc[1024];
  int t = threadIdx.x;
  int loc[9]; int s = 0;
  #pragma unroll
  for (int u = 0; u < 9; u++){ loc[u] = cnt[t*9 + u]; s += loc[u]; }
  sc[t] = s;
  __syncthreads();
  for (int off = 1; off < 1024; off <<= 1){
    int v = (t >= off) ? sc[t-off] : 0;
    __syncthreads();
    sc[t] += v;
    __syncthreads();
  }
  int run = sc[t] - s;
  #pragma unroll
  for (int u = 0; u < 9; u++){ ptr[t*9 + u] = run; run += loc[u]; }
  if (t == 1023) ptr[9216] = run;
}

// ---------------- scatter edges into (i-tile, j-tile) buckets ----------------
__global__ void k_scatter(const int* __restrict__ src, const int* __restrict__ dst,
                          const int* __restrict__ types, const float* __restrict__ w,
                          const int* __restrict__ bptr, int* __restrict__ bfill,
                          u16* __restrict__ meta, float* __restrict__ ews){
  int e = blockIdx.x * 256 + threadIdx.x;
  if (e < NE){
    int s = src[e], d = dst[e];
    int b = (s >> 4) * NJT + (d >> 6);
    int slot = bptr[b] + atomicAdd(&bfill[b], 1);
    meta[slot] = (u16)((s & 15) | ((d & 63) << 4) | (types[e] << 10));
    ews[slot] = w[e];
  }
}

// ---------------- pos -> permuted u8 bucket array ----------------
// bktP[i][ (j&~63) + (j&15)*4 + ((j>>4)&3) ] = bucket(pos[i][j])
__global__ __launch_bounds__(1024)
void k_bucket(const float* __restrict__ pos, unsigned char* __restrict__ bktP){
  int j = blockIdx.x * 1024 + threadIdx.x;
  int i = blockIdx.y;
  float spv = pos[(size_t)i*NN + j];
  int bkt;
  if (spv == 0.f) bkt = 0;
  else if (spv > 1.f) bkt = 11;
  else { float cc = fminf(fmaxf(spv * 10.f, 1.f), 10.f); bkt = (int)cc; }
  bktP[(size_t)i*NN + (j & ~63) + (j & 15)*4 + ((j >> 4) & 3)] = (unsigned char)bkt;
}

// ---------------- LDS-tiled weight transpose + bf16 convert ----------------
__global__ __launch_bounds__(256)
void k_trans(const float* __restrict__ Wq, const float* __restrict__ Wk,
             const float* __restrict__ Wv, const float* __restrict__ Wo,
             const float* __restrict__ W1, const float* __restrict__ W2,
             u16* __restrict__ Wqkvot, u16* __restrict__ W1t, u16* __restrict__ W2t){
  __shared__ u16 t_[32][33];
  int bt = blockIdx.x;   // 0..767
  const float* srcm; u16* dstm; int K, N, kt, nt;
  if (bt < 256){
    int m = bt >> 6, r = bt & 63; kt = r >> 3; nt = r & 7; K = 256; N = 256;
    srcm = (m==0)?Wq:(m==1)?Wk:(m==2)?Wv:Wo; dstm = Wqkvot + m*65536;
  } else if (bt < 512){
    int r = bt - 256; kt = r >> 5; nt = r & 31; K = 256; N = 1024; srcm = W1; dstm = W1t;
  } else {
    int r = bt - 512; kt = r >> 3; nt = r & 7; K = 1024; N = 256; srcm = W2; dstm = W2t;
  }
  int tx = threadIdx.x & 31, ty = threadIdx.x >> 5;
  #pragma unroll
  for (int s = 0; s < 4; s++)
    t_[ty + 8*s][tx] = f2bf(srcm[(size_t)(kt*32 + ty + 8*s)*N + nt*32 + tx]);
  __syncthreads();
  #pragma unroll
  for (int s = 0; s < 4; s++)
    dstm[(size_t)(nt*32 + ty + 8*s)*K + kt*32 + tx] = t_[tx][ty + 8*s];
}

// ---------------- LayerNorm (optionally fused degree-embedding add) ----------------
__global__ __launch_bounds__(256)
void k_ln(const float* __restrict__ in, const int* __restrict__ deg_in,
          const int* __restrict__ deg_out, const float* __restrict__ in_emb,
          const float* __restrict__ out_emb, const float* __restrict__ dscale,
          const float* __restrict__ g, const float* __restrict__ b,
          float* __restrict__ save_f32, u16* __restrict__ out_bf){
  int i = blockIdx.x, c = threadIdx.x;
  size_t idx = (size_t)i*DM + c;
  float val = in[idx];
  if (deg_in){
    int di = min(deg_in[i], MAXDEG), dg = min(deg_out[i], MAXDEG);
    val += (in_emb[(size_t)di*DM + c] + out_emb[(size_t)dg*DM + c]) * dscale[0];
    save_f32[idx] = val;
  }
  float s = val, s2 = val*val;
  #pragma unroll
  for (int off = 32; off; off >>= 1){
    s  += __shfl_xor(s, off);
    s2 += __shfl_xor(s2, off);
  }
  __shared__ float red[8];
  int lane = c & 63, w = c >> 6;
  if (lane == 0){ red[w] = s; red[4+w] = s2; }
  __syncthreads();
  s  = red[0] + red[1] + red[2] + red[3];
  s2 = red[4] + red[5] + red[6] + red[7];
  float mean = s * (1.f/256.f);
  float var = s2 * (1.f/256.f) - mean*mean;
  float xn = (val - mean) * rsqrtf(var + 1e-5f) * g[c] + b[c];
  out_bf[idx] = f2bf(xn);
}

// ---------------- generic MFMA GEMM, BK=64: C = A[M][K] * Bt[N][K]^T ----------------
// mode 5: QKV split epilogue (b0/b1/b2 biases; Q gets *SCALE; out=qb, out2=vT)
// mode 2: f32 out = res + val (bias b0)
// mode 3: u16 out = bf16(gelu(val)) (bias b0)
__global__ __launch_bounds__(256)
void k_gemm(const u16* __restrict__ A, const u16* __restrict__ Bt,
            const float* __restrict__ b0, const float* __restrict__ b1,
            const float* __restrict__ b2, const float* __restrict__ res,
            void* __restrict__ out, void* __restrict__ out2,
            int K, int Ncols, int mode){
  __shared__ u16 sA[64][72];
  __shared__ u16 sB[64][72];
  const int tid = threadIdx.x, lane = tid & 63, wid = tid >> 6;
  const int m0 = blockIdx.y * 64, n0 = blockIdx.x * 64;
  const int wr = (wid >> 1) * 32, wc = (wid & 1) * 32;
  const int srow = tid >> 2, scol = (tid & 3) * 16;
  const int fr = lane & 15, fg = lane >> 4;
  f32x4 acc00 = {0,0,0,0}, acc01 = {0,0,0,0}, acc10 = {0,0,0,0}, acc11 = {0,0,0,0};
  for (int k0 = 0; k0 < K; k0 += 64){
    __syncthreads();
    *(bf16x8*)&sA[srow][scol]     = *(const bf16x8*)&A[(size_t)(m0+srow)*K + k0 + scol];
    *(bf16x8*)&sA[srow][scol + 8] = *(const bf16x8*)&A[(size_t)(m0+srow)*K + k0 + scol + 8];
    *(bf16x8*)&sB[srow][scol]     = *(const bf16x8*)&Bt[(size_t)(n0+srow)*K + k0 + scol];
    *(bf16x8*)&sB[srow][scol + 8] = *(const bf16x8*)&Bt[(size_t)(n0+srow)*K + k0 + scol + 8];
    __syncthreads();
    #pragma unroll
    for (int kk = 0; kk < 2; kk++){
      bf16x8 a0  = *(const bf16x8*)&sA[wr + fr][kk*32 + fg*8];
      bf16x8 a1  = *(const bf16x8*)&sA[wr + 16 + fr][kk*32 + fg*8];
      bf16x8 b0f = *(const bf16x8*)&sB[wc + fr][kk*32 + fg*8];
      bf16x8 b1f = *(const bf16x8*)&sB[wc + 16 + fr][kk*32 + fg*8];
      acc00 = MFMA16(a0, b0f, acc00, 0, 0, 0);
      acc01 = MFMA16(a0, b1f, acc01, 0, 0, 0);
      acc10 = MFMA16(a1, b0f, acc10, 0, 0, 0);
      acc11 = MFMA16(a1, b1f, acc11, 0, 0, 0);
    }
  }
  #pragma unroll
  for (int fm = 0; fm < 2; fm++)
  #pragma unroll
  for (int fn = 0; fn < 2; fn++){
    f32x4 c = (fm==0) ? ((fn==0) ? acc00 : acc01) : ((fn==0) ? acc10 : acc11);
    #pragma unroll
    for (int r = 0; r < 4; r++){
      int row = m0 + wr + fm*16 + fg*4 + r;
      int col = n0 + wc + fn*16 + fr;
      if (mode == 5){
        int seg = col >> 8, cn = col & 255;
        const float* bp = (seg==0) ? b0 : (seg==1) ? b1 : b2;
        float val = c[r] + bp[cn];
        if (seg == 0) val *= 0.70710678f;   // fold score scale into Q
        if (seg < 2) ((u16*)out)[(size_t)seg*NN*DM + (size_t)row*DM + cn] = f2bf(val);
        else         ((u16*)out2)[(size_t)cn*NN + row] = f2bf(val);
      } else {
        float val = c[r] + b0[col];
        size_t idx = (size_t)row*Ncols + col;
        if (mode == 2) ((float*)out)[idx] = res[idx] + val;
        else           ((u16*)out)[idx] = f2bf(0.5f*val*(1.f + erff(val*0.70710678f)));
      }
    }
  }
}

// ---------------- barrier-free per-wave fused attention, prefetch-pipelined ----------------
// WG = 256 = 4 waves; wave w = head (blockIdx.z*4 + w) for 16 q-rows;
// grid (192 i-tiles, JSPLIT j-chunks, 2 head-groups).
// Next-tile K/bucket loads issued at iteration top (register double-buffer);
// vT loads hoisted before the LDS phase. Wave-private LDS planes, zero barriers.
__global__ __launch_bounds__(256, 5)
void k_attn(const u16* __restrict__ qb, const u16* __restrict__ kb, const u16* __restrict__ vT,
            const unsigned char* __restrict__ bktP,
            const float* __restrict__ spd_table, const float* __restrict__ slb,
            const u16* __restrict__ meta, const float* __restrict__ ews,
            const float* __restrict__ ett, const int* __restrict__ bptr,
            float* __restrict__ opart, float* __restrict__ mpart, float* __restrict__ lpart){
  __shared__ float s_sc[4][16][68];
  __shared__ float s_spdw[4][32];
  __shared__ float s_ettw[4][32];
  const int tid = threadIdx.x, lane = tid & 63, w = tid >> 6;
  const int h = (blockIdx.z << 2) | w;
  const int it = blockIdx.x, jc = blockIdx.y;
  const int i0 = it * 16;
  // wave-private table init (same-wave ds_write -> ds_read, no barrier needed)
  if (lane < 12) s_spdw[w][lane] = spd_table[lane*8 + h] * 10.f;
  if (lane < 16) s_ettw[w][lane] = ett[lane*8 + h] * 10.f;
  const float slbh = slb[h];
  const int fr = lane & 15, fg = lane >> 4;
  bf16x8 qv = *(const bf16x8*)&qb[(size_t)(i0 + fr)*DM + h*HDIM + fg*8];
  float (*sc)[68] = s_sc[w];
  f32x4 o0 = {0,0,0,0}, o1 = {0,0,0,0};
  float m_run = -3.0e38f, l_run = 0.f;

  const int jt0 = jc * (NJT/JSPLIT), jt1 = jt0 + NJT/JSPLIT;

  // current-tile register buffers (prologue load)
  bf16x8 kf0, kf1, kf2, kf3;
  uchar4 bk0, bk1, bk2, bk3;
  {
    const int j0 = jt0 * 64;
    kf0 = *(const bf16x8*)&kb[(size_t)(j0      + fr)*DM + h*HDIM + fg*8];
    kf1 = *(const bf16x8*)&kb[(size_t)(j0 + 16 + fr)*DM + h*HDIM + fg*8];
    kf2 = *(const bf16x8*)&kb[(size_t)(j0 + 32 + fr)*DM + h*HDIM + fg*8];
    kf3 = *(const bf16x8*)&kb[(size_t)(j0 + 48 + fr)*DM + h*HDIM + fg*8];
    bk0 = *(const uchar4*)&bktP[(size_t)(i0 + fg*4 + 0)*NN + j0 + fr*4];
    bk1 = *(const uchar4*)&bktP[(size_t)(i0 + fg*4 + 1)*NN + j0 + fr*4];
    bk2 = *(const uchar4*)&bktP[(size_t)(i0 + fg*4 + 2)*NN + j0 + fr*4];
    bk3 = *(const uchar4*)&bktP[(size_t)(i0 + fg*4 + 3)*NN + j0 + fr*4];
  }

  #pragma unroll 2
  for (int jt = jt0; jt < jt1; ++jt){
    const int j0 = jt * 64;
    // ---- issue NEXT tile loads (consumed next iteration; clamp keeps in-bounds) ----
    int jn = j0 + 64; if (jn > NN - 64) jn = NN - 64;
    bf16x8 nkf0 = *(const bf16x8*)&kb[(size_t)(jn      + fr)*DM + h*HDIM + fg*8];
    bf16x8 nkf1 = *(const bf16x8*)&kb[(size_t)(jn + 16 + fr)*DM + h*HDIM + fg*8];
    bf16x8 nkf2 = *(const bf16x8*)&kb[(size_t)(jn + 32 + fr)*DM + h*HDIM + fg*8];
    bf16x8 nkf3 = *(const bf16x8*)&kb[(size_t)(jn + 48 + fr)*DM + h*HDIM + fg*8];
    uchar4 nbk0 = *(const uchar4*)&bktP[(size_t)(i0 + fg*4 + 0)*NN + jn + fr*4];
    uchar4 nbk1 = *(const uchar4*)&bktP[(size_t)(i0 + fg*4 + 1)*NN + jn + fr*4];
    uchar4 nbk2 = *(const uchar4*)&bktP[(size_t)(i0 + fg*4 + 2)*NN + jn + fr*4];
    uchar4 nbk3 = *(const uchar4*)&bktP[(size_t)(i0 + fg*4 + 3)*NN + jn + fr*4];
    // ---- vT loads for CURRENT tile (consumed at PV, ~1000cy later) ----
    bf16x8 vf00 = *(const bf16x8*)&vT[(size_t)(h*HDIM      + fr)*NN + j0      + fg*8];
    bf16x8 vf01 = *(const bf16x8*)&vT[(size_t)(h*HDIM      + fr)*NN + j0 + 32 + fg*8];
    bf16x8 vf10 = *(const bf16x8*)&vT[(size_t)(h*HDIM + 16 + fr)*NN + j0      + fg*8];
    bf16x8 vf11 = *(const bf16x8*)&vT[(size_t)(h*HDIM + 16 + fr)*NN + j0 + 32 + fg*8];
    // ---- edge range (scalar loads, issued early) ----
    int e0 = bptr[it*NJT + jt], e1 = bptr[it*NJT + jt + 1];

    // ---- QK^T on CURRENT regs (resident since last iteration) ----
    f32x4 z = {0,0,0,0};
    f32x4 s0 = MFMA16(qv, kf0, z, 0, 0, 0);
    f32x4 s1 = MFMA16(qv, kf1, z, 0, 0, 0);
    f32x4 s2 = MFMA16(qv, kf2, z, 0, 0, 0);
    f32x4 s3 = MFMA16(qv, kf3, z, 0, 0, 0);
    // ---- scores + spd/diag bias -> wave-private LDS plane ----
    unsigned char bb[4][4] = {{bk0.x,bk0.y,bk0.z,bk0.w},{bk1.x,bk1.y,bk1.z,bk1.w},
                              {bk2.x,bk2.y,bk2.z,bk2.w},{bk3.x,bk3.y,bk3.z,bk3.w}};
    const bool dg_tile = (j0 == (i0 & ~63));
    #pragma unroll
    for (int r = 0; r < 4; r++){
      int row = fg*4 + r;
      #pragma unroll
      for (int c2 = 0; c2 < 4; c2++){
        int col = c2*16 + fr;
        float sv = (c2==0) ? s0[r] : (c2==1) ? s1[r] : (c2==2) ? s2[r] : s3[r];
        float val = sv + s_spdw[w][(int)bb[r][c2]];
        if (dg_tile && (i0 + row == j0 + col)) val += slbh;
        sc[row][col] = val;
      }
    }
    // ---- edge bias: one LDS atomic per edge (plain ds ops, divergence-safe) ----
    for (int ix = e0 + lane; ix < e1; ix += 64){
      u16 me = meta[ix];
      int il = me & 15, jl = (me >> 4) & 63, tp = me >> 10;
      atomicAdd(&sc[il][jl], s_ettw[w][tp] + 200.f * ews[ix]);
    }
    // ---- read back in A-fragment layout (row fr, cols fg*8.. & 32+fg*8..) ----
    float v[16];
    { f32x4 a = *(const f32x4*)&sc[fr][fg*8];
      v[0]=a[0]; v[1]=a[1]; v[2]=a[2]; v[3]=a[3]; }
    { f32x4 a = *(const f32x4*)&sc[fr][fg*8 + 4];
      v[4]=a[0]; v[5]=a[1]; v[6]=a[2]; v[7]=a[3]; }
    { f32x4 a = *(const f32x4*)&sc[fr][32 + fg*8];
      v[8]=a[0]; v[9]=a[1]; v[10]=a[2]; v[11]=a[3]; }
    { f32x4 a = *(const f32x4*)&sc[fr][32 + fg*8 + 4];
      v[12]=a[0]; v[13]=a[1]; v[14]=a[2]; v[15]=a[3]; }
    // ---- online softmax (row fr; col-groups across fg) ----
    float mx = v[0];
    #pragma unroll
    for (int t = 1; t < 16; t++) mx = fmaxf(mx, v[t]);
    mx = fmaxf(mx, __shfl_xor(mx, 16));
    mx = fmaxf(mx, __shfl_xor(mx, 32));
    float mnew = fmaxf(m_run, mx);
    float fac = __expf(m_run - mnew);
    float p[16], ps = 0.f;
    #pragma unroll
    for (int t = 0; t < 16; t++){ p[t] = __expf(v[t] - mnew); ps += p[t]; }
    ps += __shfl_xor(ps, 16);
    ps += __shfl_xor(ps, 32);
    l_run = l_run * fac + ps;
    m_run = mnew;
    // ---- redistribute fac to accumulator rows (fg*4+r), rescale ----
    float f0 = __shfl(fac, fg*4 + 0);
    float f1 = __shfl(fac, fg*4 + 1);
    float f2 = __shfl(fac, fg*4 + 2);
    float f3 = __shfl(fac, fg*4 + 3);
    o0[0]*=f0; o0[1]*=f1; o0[2]*=f2; o0[3]*=f3;
    o1[0]*=f0; o1[1]*=f1; o1[2]*=f2; o1[3]*=f3;
    // ---- P -> bf16 (packed cvt), PV with pre-loaded vT ----
    union { u32 wd[4]; bf16x8 v8; } pa0u, pa1u;
    #pragma unroll
    for (int t = 0; t < 4; t++){
      pa0u.wd[t] = cvtpk(p[2*t], p[2*t+1]);
      pa1u.wd[t] = cvtpk(p[8 + 2*t], p[9 + 2*t]);
    }
    o0 = MFMA16(pa0u.v8, vf00, o0, 0, 0, 0);
    o0 = MFMA16(pa1u.v8, vf01, o0, 0, 0, 0);
    o1 = MFMA16(pa0u.v8, vf10, o1, 0, 0, 0);
    o1 = MFMA16(pa1u.v8, vf11, o1, 0, 0, 0);
    // ---- rotate prefetch buffers ----
    kf0 = nkf0; kf1 = nkf1; kf2 = nkf2; kf3 = nkf3;
    bk0 = nbk0; bk1 = nbk1; bk2 = nbk2; bk3 = nbk3;
  }

  // ---- write unnormalized partials ----
  float* ob = opart + (size_t)jc*NN*DM;
  #pragma unroll
  for (int r = 0; r < 4; r++){
    size_t row = i0 + fg*4 + r;
    ob[row*DM + h*HDIM + fr]      = o0[r];
    ob[row*DM + h*HDIM + 16 + fr] = o1[r];
  }
  if (fg == 0){
    mpart[jc*NN*NH + (i0 + fr)*NH + h] = m_run;
    lpart[jc*NN*NH + (i0 + fr)*NH + h] = l_run;
  }
}

// ---------------- combine J-split partials ----------------
__global__ __launch_bounds__(256)
void k_reduce(const float* __restrict__ opart, const float* __restrict__ mpart,
              const float* __restrict__ lpart, u16* __restrict__ aob){
  int row = blockIdx.x, col = threadIdx.x, h = col >> 5;
  float m[JSPLIT], l[JSPLIT];
  float M = -3.0e38f;
  #pragma unroll
  for (int jc = 0; jc < JSPLIT; jc++){
    m[jc] = mpart[jc*NN*NH + row*NH + h];
    l[jc] = lpart[jc*NN*NH + row*NH + h];
    M = fmaxf(M, m[jc]);
  }
  float L = 0.f, acc = 0.f;
  #pragma unroll
  for (int jc = 0; jc < JSPLIT; jc++){
    float w = __expf(m[jc] - M);
    L += l[jc] * w;
    acc += opart[(size_t)jc*NN*DM + (size_t)row*DM + col] * w;
  }
  aob[(size_t)row*DM + col] = f2bf(acc / L);
}

// ---------------- launcher ----------------
extern "C" void kernel_launch(void* const* d_in, const int* in_sizes, int n_in,
                              void* d_out, int out_size, void* d_ws, size_t ws_size,
                              hipStream_t stream){
  const float* x     = (const float*)d_in[0];
  const int*   ei    = (const int*)d_in[1];
  const int*   etyp  = (const int*)d_in[2];
  const float* pos   = (const float*)d_in[3];
  const float* ewin  = (const float*)d_in[4];
  const float* Wq    = (const float*)d_in[5];
  const float* bq    = (const float*)d_in[6];
  const float* Wk    = (const float*)d_in[7];
  const float* bk    = (const float*)d_in[8];
  const float* Wv    = (const float*)d_in[9];
  const float* bv    = (const float*)d_in[10];
  const float* Wo    = (const float*)d_in[11];
  const float* bo    = (const float*)d_in[12];
  const float* spd   = (const float*)d_in[13];
  const float* ett   = (const float*)d_in[14];
  const float* slb   = (const float*)d_in[15];
  const float* inde  = (const float*)d_in[16];
  const float* outde = (const float*)d_in[17];
  const float* dsc   = (const float*)d_in[18];
  const float* ln1g  = (const float*)d_in[19];
  const float* ln1b  = (const float*)d_in[20];
  const float* ln2g  = (const float*)d_in[21];
  const float* ln2b  = (const float*)d_in[22];
  const float* W1    = (const float*)d_in[23];
  const float* b1    = (const float*)d_in[24];
  const float* W2    = (const float*)d_in[25];
  const float* b2    = (const float*)d_in[26];
  const int* src = ei;
  const int* dst = ei + NE;

  char* p = (char*)d_ws;
  auto alloc = [&](size_t bytes) -> void* {
    void* r = (void*)p;
    p += (bytes + 255) & ~(size_t)255;
    return r;
  };
  // zeroed region (contiguous): deg_in, deg_out, bcnt, bfill
  int*  deg_in  = (int*)alloc(NN*4);
  int*  deg_out = (int*)alloc(NN*4);
  int*  bcnt    = (int*)alloc(9216*4);
  int*  bfill   = (int*)alloc(9216*4);
  int*  bptr    = (int*)alloc(9217*4);
  u16*  meta    = (u16*)alloc(NE*2);
  float* ews    = (float*)alloc(NE*4);
  unsigned char* bktP = (unsigned char*)alloc((size_t)NN*NN);
  float* xb     = (float*)alloc((size_t)NN*DM*4);
  float* x2     = (float*)alloc((size_t)NN*DM*4);
  u16*  xnb     = (u16*)alloc((size_t)NN*DM*2);
  u16*  x2nb    = (u16*)alloc((size_t)NN*DM*2);
  u16*  qb      = (u16*)alloc((size_t)NN*DM*2);   // qb, kb contiguous
  u16*  kb      = (u16*)alloc((size_t)NN*DM*2);
  u16*  vT      = (u16*)alloc((size_t)NN*DM*2);
  u16*  aob     = (u16*)alloc((size_t)NN*DM*2);
  u16*  h1b     = (u16*)alloc((size_t)NN*DFF*2);
  float* opart  = (float*)alloc((size_t)JSPLIT*NN*DM*4);
  float* mpart  = (float*)alloc((size_t)JSPLIT*NN*NH*4);
  float* lpart  = (float*)alloc((size_t)JSPLIT*NN*NH*4);
  u16*  Wqkvot  = (u16*)alloc(4*65536*2);          // Wq^T,Wk^T,Wv^T,Wo^T contiguous
  u16*  W1t     = (u16*)alloc(262144*2);
  u16*  W2t     = (u16*)alloc(262144*2);

  hipMemsetAsync(deg_in, 0, (2*NN + 2*9216)*4, stream);

  k_deg<<<NE/256, 256, 0, stream>>>(src, dst, deg_out, deg_in, bcnt);
  k_scan<<<1, 1024, 0, stream>>>(bcnt, bptr);
  k_scatter<<<NE/256, 256, 0, stream>>>(src, dst, etyp, ewin, bptr, bfill, meta, ews);
  k_bucket<<<dim3(3, NN), 1024, 0, stream>>>(pos, bktP);
  k_trans<<<768, 256, 0, stream>>>(Wq, Wk, Wv, Wo, W1, W2, Wqkvot, W1t, W2t);
  k_ln<<<NN, 256, 0, stream>>>(x, deg_in, deg_out, inde, outde, dsc, ln1g, ln1b, xb, xnb);

  // fused QKV: Bt = [Wq^T; Wk^T; Wv^T] (768 x 256)
  k_gemm<<<dim3(12, 48), 256, 0, stream>>>(xnb, Wqkvot, bq, bk, bv, nullptr,
                                           qb, vT, DM, 768, 5);

  k_attn<<<dim3(NIT, JSPLIT, 2), 256, 0, stream>>>(qb, kb, vT, bktP, spd, slb, meta, ews,
                                                   ett, bptr, opart, mpart, lpart);
  k_reduce<<<NN, 256, 0, stream>>>(opart, mpart, lpart, aob);

  u16* Wot = Wqkvot + 3*65536;
  k_gemm<<<dim3(4, 48), 256, 0, stream>>>(aob, Wot, bo, nullptr, nullptr, xb,
                                          x2, nullptr, DM, DM, 2);
  k_ln<<<NN, 256, 0, stream>>>(x2, nullptr, nullptr, nullptr, nullptr, nullptr,
                               ln2g, ln2b, nullptr, x2nb);
  k_gemm<<<dim3(16, 48), 256, 0, stream>>>(x2nb, W1t, b1, nullptr, nullptr, nullptr,
                                           h1b, nullptr, DM, DFF, 3);
  k_gemm<<<dim3(4, 48), 256, 0, stream>>>(h1b, W2t, b2, nullptr, nullptr, x2,
                                          d_out, nullptr, DFF, DM, 2);
}

// Round 13
// 318.025 us; speedup vs baseline: 1.2558x; 1.2558x over previous
//
#include <hip/hip_runtime.h>
#include <hip/hip_bf16.h>

#define NN 3072
#define DM 256
#define NH 8
#define HDIM 32
#define NE 98304
#define DFF 1024
#define MAXDEG 512
#define NIT 192   // NN/16 i-tiles
#define NJT 48    // NN/64 j-tiles
#define JSPLIT 4

typedef short bf16x8 __attribute__((ext_vector_type(8)));
typedef float f32x4 __attribute__((ext_vector_type(4)));
typedef unsigned short u16;
typedef unsigned int u32;

#define MFMA16 __builtin_amdgcn_mfma_f32_16x16x32_bf16

__device__ __forceinline__ u16 f2bf(float f){
  u32 u = __builtin_bit_cast(u32, f);
  u32 r = (u + 0x7FFFu + ((u >> 16) & 1u)) >> 16;
  return (u16)r;
}
__device__ __forceinline__ u32 cvtpk(float lo, float hi){
  u32 r; asm("v_cvt_pk_bf16_f32 %0, %1, %2" : "=v"(r) : "v"(lo), "v"(hi)); return r;
}

// ---------------- degree + bucket count ----------------
__global__ void k_deg(const int* __restrict__ src, const int* __restrict__ dst,
                      int* __restrict__ deg_out, int* __restrict__ deg_in,
                      int* __restrict__ bcnt){
  int e = blockIdx.x * 256 + threadIdx.x;
  if (e < NE){
    int s = src[e], d = dst[e];
    atomicAdd(&deg_out[s], 1);
    atomicAdd(&deg_in[d], 1);
    atomicAdd(&bcnt[(s >> 4) * NJT + (d >> 6)], 1);
  }
}

// ---------------- exclusive scan of bcnt[9216] -> bptr[9217] ----------------
__global__ __launch_bounds__(1024)
void k_scan(const int* __restrict__ cnt, int* __restrict__ ptr){
  __shared__ int sc[1024];
  int t = threadIdx.x;
  int loc[9]; int s = 0;
  #pragma unroll
  for (int u = 0; u < 9; u++){ loc[u] = cnt[t*9 + u]; s += loc[u]; }
  sc[t] = s;
  __syncthreads();
  for (int off = 1; off < 1024; off <<= 1){
    int v = (t >= off) ? sc[t-off] : 0;
    __syncthreads();
    sc[t] += v;
    __syncthreads();
  }
  int run = sc[t] - s;
  #pragma unroll
  for (int u = 0; u < 9; u++){ ptr[t*9 + u] = run; run += loc[u]; }
  if (t == 1023) ptr[9216] = run;
}

// ---------------- scatter edges into (i-tile, j-tile) buckets ----------------
__global__ void k_scatter(const int* __restrict__ src, const int* __restrict__ dst,
                          const int* __restrict__ types, const float* __restrict__ w,
                          const int* __restrict__ bptr, int* __restrict__ bfill,
                          u16* __restrict__ meta, float* __restrict__ ews){
  int e = blockIdx.x * 256 + threadIdx.x;
  if (e < NE){
    int s = src[e], d = dst[e];
    int b = (s >> 4) * NJT + (d >> 6);
    int slot = bptr[b] + atomicAdd(&bfill[b], 1);
    meta[slot] = (u16)((s & 15) | ((d & 63) << 4) | (types[e] << 10));
    ews[slot] = w[e];
  }
}

// ---------------- pos -> permuted u8 bucket array ----------------
// bktP[i][ (j&~63) + (j&15)*4 + ((j>>4)&3) ] = bucket(pos[i][j])
__global__ __launch_bounds__(1024)
void k_bucket(const float* __restrict__ pos, unsigned char* __restrict__ bktP){
  int j = blockIdx.x * 1024 + threadIdx.x;
  int i = blockIdx.y;
  float spv = pos[(size_t)i*NN + j];
  int bkt;
  if (spv == 0.f) bkt = 0;
  else if (spv > 1.f) bkt = 11;
  else { float cc = fminf(fmaxf(spv * 10.f, 1.f), 10.f); bkt = (int)cc; }
  bktP[(size_t)i*NN + (j & ~63) + (j & 15)*4 + ((j >> 4) & 3)] = (unsigned char)bkt;
}

// ---------------- LDS-tiled weight transpose + bf16 convert ----------------
__global__ __launch_bounds__(256)
void k_trans(const float* __restrict__ Wq, const float* __restrict__ Wk,
             const float* __restrict__ Wv, const float* __restrict__ Wo,
             const float* __restrict__ W1, const float* __restrict__ W2,
             u16* __restrict__ Wqkvot, u16* __restrict__ W1t, u16* __restrict__ W2t){
  __shared__ u16 t_[32][33];
  int bt = blockIdx.x;   // 0..767
  const float* srcm; u16* dstm; int K, N, kt, nt;
  if (bt < 256){
    int m = bt >> 6, r = bt & 63; kt = r >> 3; nt = r & 7; K = 256; N = 256;
    srcm = (m==0)?Wq:(m==1)?Wk:(m==2)?Wv:Wo; dstm = Wqkvot + m*65536;
  } else if (bt < 512){
    int r = bt - 256; kt = r >> 5; nt = r & 31; K = 256; N = 1024; srcm = W1; dstm = W1t;
  } else {
    int r = bt - 512; kt = r >> 3; nt = r & 7; K = 1024; N = 256; srcm = W2; dstm = W2t;
  }
  int tx = threadIdx.x & 31, ty = threadIdx.x >> 5;
  #pragma unroll
  for (int s = 0; s < 4; s++)
    t_[ty + 8*s][tx] = f2bf(srcm[(size_t)(kt*32 + ty + 8*s)*N + nt*32 + tx]);
  __syncthreads();
  #pragma unroll
  for (int s = 0; s < 4; s++)
    dstm[(size_t)(nt*32 + ty + 8*s)*K + kt*32 + tx] = t_[tx][ty + 8*s];
}

// ---------------- LayerNorm (optionally fused degree-embedding add) ----------------
__global__ __launch_bounds__(256)
void k_ln(const float* __restrict__ in, const int* __restrict__ deg_in,
          const int* __restrict__ deg_out, const float* __restrict__ in_emb,
          const float* __restrict__ out_emb, const float* __restrict__ dscale,
          const float* __restrict__ g, const float* __restrict__ b,
          float* __restrict__ save_f32, u16* __restrict__ out_bf){
  int i = blockIdx.x, c = threadIdx.x;
  size_t idx = (size_t)i*DM + c;
  float val = in[idx];
  if (deg_in){
    int di = min(deg_in[i], MAXDEG), dg = min(deg_out[i], MAXDEG);
    val += (in_emb[(size_t)di*DM + c] + out_emb[(size_t)dg*DM + c]) * dscale[0];
    save_f32[idx] = val;
  }
  float s = val, s2 = val*val;
  #pragma unroll
  for (int off = 32; off; off >>= 1){
    s  += __shfl_xor(s, off);
    s2 += __shfl_xor(s2, off);
  }
  __shared__ float red[8];
  int lane = c & 63, w = c >> 6;
  if (lane == 0){ red[w] = s; red[4+w] = s2; }
  __syncthreads();
  s  = red[0] + red[1] + red[2] + red[3];
  s2 = red[4] + red[5] + red[6] + red[7];
  float mean = s * (1.f/256.f);
  float var = s2 * (1.f/256.f) - mean*mean;
  float xn = (val - mean) * rsqrtf(var + 1e-5f) * g[c] + b[c];
  out_bf[idx] = f2bf(xn);
}

// ---------------- generic MFMA GEMM, BK=64: C = A[M][K] * Bt[N][K]^T ----------------
// mode 5: QKV split epilogue (b0/b1/b2 biases; Q gets *SCALE; out=qb, out2=vT)
// mode 2: f32 out = res + val (bias b0)
// mode 3: u16 out = bf16(gelu(val)) (bias b0)
__global__ __launch_bounds__(256)
void k_gemm(const u16* __restrict__ A, const u16* __restrict__ Bt,
            const float* __restrict__ b0, const float* __restrict__ b1,
            const float* __restrict__ b2, const float* __restrict__ res,
            void* __restrict__ out, void* __restrict__ out2,
            int K, int Ncols, int mode){
  __shared__ u16 sA[64][72];
  __shared__ u16 sB[64][72];
  const int tid = threadIdx.x, lane = tid & 63, wid = tid >> 6;
  const int m0 = blockIdx.y * 64, n0 = blockIdx.x * 64;
  const int wr = (wid >> 1) * 32, wc = (wid & 1) * 32;
  const int srow = tid >> 2, scol = (tid & 3) * 16;
  const int fr = lane & 15, fg = lane >> 4;
  f32x4 acc00 = {0,0,0,0}, acc01 = {0,0,0,0}, acc10 = {0,0,0,0}, acc11 = {0,0,0,0};
  for (int k0 = 0; k0 < K; k0 += 64){
    __syncthreads();
    *(bf16x8*)&sA[srow][scol]     = *(const bf16x8*)&A[(size_t)(m0+srow)*K + k0 + scol];
    *(bf16x8*)&sA[srow][scol + 8] = *(const bf16x8*)&A[(size_t)(m0+srow)*K + k0 + scol + 8];
    *(bf16x8*)&sB[srow][scol]     = *(const bf16x8*)&Bt[(size_t)(n0+srow)*K + k0 + scol];
    *(bf16x8*)&sB[srow][scol + 8] = *(const bf16x8*)&Bt[(size_t)(n0+srow)*K + k0 + scol + 8];
    __syncthreads();
    #pragma unroll
    for (int kk = 0; kk < 2; kk++){
      bf16x8 a0  = *(const bf16x8*)&sA[wr + fr][kk*32 + fg*8];
      bf16x8 a1  = *(const bf16x8*)&sA[wr + 16 + fr][kk*32 + fg*8];
      bf16x8 b0f = *(const bf16x8*)&sB[wc + fr][kk*32 + fg*8];
      bf16x8 b1f = *(const bf16x8*)&sB[wc + 16 + fr][kk*32 + fg*8];
      acc00 = MFMA16(a0, b0f, acc00, 0, 0, 0);
      acc01 = MFMA16(a0, b1f, acc01, 0, 0, 0);
      acc10 = MFMA16(a1, b0f, acc10, 0, 0, 0);
      acc11 = MFMA16(a1, b1f, acc11, 0, 0, 0);
    }
  }
  #pragma unroll
  for (int fm = 0; fm < 2; fm++)
  #pragma unroll
  for (int fn = 0; fn < 2; fn++){
    f32x4 c = (fm==0) ? ((fn==0) ? acc00 : acc01) : ((fn==0) ? acc10 : acc11);
    #pragma unroll
    for (int r = 0; r < 4; r++){
      int row = m0 + wr + fm*16 + fg*4 + r;
      int col = n0 + wc + fn*16 + fr;
      if (mode == 5){
        int seg = col >> 8, cn = col & 255;
        const float* bp = (seg==0) ? b0 : (seg==1) ? b1 : b2;
        float val = c[r] + bp[cn];
        if (seg == 0) val *= 0.70710678f;   // fold score scale into Q
        if (seg < 2) ((u16*)out)[(size_t)seg*NN*DM + (size_t)row*DM + cn] = f2bf(val);
        else         ((u16*)out2)[(size_t)cn*NN + row] = f2bf(val);
      } else {
        float val = c[r] + b0[col];
        size_t idx = (size_t)row*Ncols + col;
        if (mode == 2) ((float*)out)[idx] = res[idx] + val;
        else           ((u16*)out)[idx] = f2bf(0.5f*val*(1.f + erff(val*0.70710678f)));
      }
    }
  }
}

// ---------------- barrier-free per-wave fused attention, prefetch-pipelined ----------------
// WG = 512 = 8 waves; wave h = head h for 16 q-rows; grid (192 i-tiles, JSPLIT j-chunks).
// Round-9 structure (83us, no spills) + register prefetch of next-tile K/buckets and
// hoisted vT/edge-range loads. NO min-waves clamp: allocator free (~110 VGPR, no spill).
__global__ __launch_bounds__(512)
void k_attn(const u16* __restrict__ qb, const u16* __restrict__ kb, const u16* __restrict__ vT,
            const unsigned char* __restrict__ bktP,
            const float* __restrict__ spd_table, const float* __restrict__ slb,
            const u16* __restrict__ meta, const float* __restrict__ ews,
            const float* __restrict__ ett, const int* __restrict__ bptr,
            float* __restrict__ opart, float* __restrict__ mpart, float* __restrict__ lpart){
  __shared__ float s_sc[NH][16][68];
  __shared__ float s_spdw[NH][32];
  __shared__ float s_ettw[NH][32];
  const int tid = threadIdx.x, lane = tid & 63, h = tid >> 6;
  const int it = blockIdx.x, jc = blockIdx.y;
  const int i0 = it * 16;
  // wave-private table init (same-wave ds_write -> ds_read, no barrier needed)
  if (lane < 12) s_spdw[h][lane] = spd_table[lane*8 + h] * 10.f;
  if (lane < 16) s_ettw[h][lane] = ett[lane*8 + h] * 10.f;
  const float slbh = slb[h];
  const int fr = lane & 15, fg = lane >> 4;
  bf16x8 qv = *(const bf16x8*)&qb[(size_t)(i0 + fr)*DM + h*HDIM + fg*8];
  float (*sc)[68] = s_sc[h];
  f32x4 o0 = {0,0,0,0}, o1 = {0,0,0,0};
  float m_run = -3.0e38f, l_run = 0.f;

  const int jt0 = jc * (NJT/JSPLIT), jt1 = jt0 + NJT/JSPLIT;

  // current-tile register buffers (prologue load)
  bf16x8 kf0, kf1, kf2, kf3;
  uchar4 bk0, bk1, bk2, bk3;
  {
    const int j0 = jt0 * 64;
    kf0 = *(const bf16x8*)&kb[(size_t)(j0      + fr)*DM + h*HDIM + fg*8];
    kf1 = *(const bf16x8*)&kb[(size_t)(j0 + 16 + fr)*DM + h*HDIM + fg*8];
    kf2 = *(const bf16x8*)&kb[(size_t)(j0 + 32 + fr)*DM + h*HDIM + fg*8];
    kf3 = *(const bf16x8*)&kb[(size_t)(j0 + 48 + fr)*DM + h*HDIM + fg*8];
    bk0 = *(const uchar4*)&bktP[(size_t)(i0 + fg*4 + 0)*NN + j0 + fr*4];
    bk1 = *(const uchar4*)&bktP[(size_t)(i0 + fg*4 + 1)*NN + j0 + fr*4];
    bk2 = *(const uchar4*)&bktP[(size_t)(i0 + fg*4 + 2)*NN + j0 + fr*4];
    bk3 = *(const uchar4*)&bktP[(size_t)(i0 + fg*4 + 3)*NN + j0 + fr*4];
  }

  for (int jt = jt0; jt < jt1; ++jt){
    const int j0 = jt * 64;
    // ---- issue NEXT-tile loads early (consumed next iteration; clamped in-bounds) ----
    int jn = j0 + 64; if (jn > NN - 64) jn = NN - 64;
    bf16x8 nkf0 = *(const bf16x8*)&kb[(size_t)(jn      + fr)*DM + h*HDIM + fg*8];
    bf16x8 nkf1 = *(const bf16x8*)&kb[(size_t)(jn + 16 + fr)*DM + h*HDIM + fg*8];
    bf16x8 nkf2 = *(const bf16x8*)&kb[(size_t)(jn + 32 + fr)*DM + h*HDIM + fg*8];
    bf16x8 nkf3 = *(const bf16x8*)&kb[(size_t)(jn + 48 + fr)*DM + h*HDIM + fg*8];
    uchar4 nbk0 = *(const uchar4*)&bktP[(size_t)(i0 + fg*4 + 0)*NN + jn + fr*4];
    uchar4 nbk1 = *(const uchar4*)&bktP[(size_t)(i0 + fg*4 + 1)*NN + jn + fr*4];
    uchar4 nbk2 = *(const uchar4*)&bktP[(size_t)(i0 + fg*4 + 2)*NN + jn + fr*4];
    uchar4 nbk3 = *(const uchar4*)&bktP[(size_t)(i0 + fg*4 + 3)*NN + jn + fr*4];
    // ---- vT loads for CURRENT tile (consumed at PV after the whole LDS phase) ----
    bf16x8 vf00 = *(const bf16x8*)&vT[(size_t)(h*HDIM      + fr)*NN + j0      + fg*8];
    bf16x8 vf01 = *(const bf16x8*)&vT[(size_t)(h*HDIM      + fr)*NN + j0 + 32 + fg*8];
    bf16x8 vf10 = *(const bf16x8*)&vT[(size_t)(h*HDIM + 16 + fr)*NN + j0      + fg*8];
    bf16x8 vf11 = *(const bf16x8*)&vT[(size_t)(h*HDIM + 16 + fr)*NN + j0 + 32 + fg*8];
    // ---- edge range (scalar loads, issued early) ----
    int e0 = bptr[it*NJT + jt], e1 = bptr[it*NJT + jt + 1];

    // ---- QK^T on CURRENT regs (resident since previous iteration) ----
    f32x4 z = {0,0,0,0};
    f32x4 s0 = MFMA16(qv, kf0, z, 0, 0, 0);
    f32x4 s1 = MFMA16(qv, kf1, z, 0, 0, 0);
    f32x4 s2 = MFMA16(qv, kf2, z, 0, 0, 0);
    f32x4 s3 = MFMA16(qv, kf3, z, 0, 0, 0);
    // ---- scores + spd/diag bias -> wave-private LDS plane ----
    unsigned char bb[4][4] = {{bk0.x,bk0.y,bk0.z,bk0.w},{bk1.x,bk1.y,bk1.z,bk1.w},
                              {bk2.x,bk2.y,bk2.z,bk2.w},{bk3.x,bk3.y,bk3.z,bk3.w}};
    const bool dg_tile = (j0 == (i0 & ~63));
    #pragma unroll
    for (int r = 0; r < 4; r++){
      int row = fg*4 + r;
      #pragma unroll
      for (int c2 = 0; c2 < 4; c2++){
        int col = c2*16 + fr;
        float sv = (c2==0) ? s0[r] : (c2==1) ? s1[r] : (c2==2) ? s2[r] : s3[r];
        float val = sv + s_spdw[h][(int)bb[r][c2]];
        if (dg_tile && (i0 + row == j0 + col)) val += slbh;
        sc[row][col] = val;
      }
    }
    // ---- edge bias: one LDS atomic per edge (plain ds ops, divergence-safe) ----
    for (int ix = e0 + lane; ix < e1; ix += 64){
      u16 me = meta[ix];
      int il = me & 15, jl = (me >> 4) & 63, tp = me >> 10;
      atomicAdd(&sc[il][jl], s_ettw[h][tp] + 200.f * ews[ix]);
    }
    // ---- read back in A-fragment layout (row fr, cols fg*8.. & 32+fg*8..) ----
    float v[16];
    { f32x4 a = *(const f32x4*)&sc[fr][fg*8];
      v[0]=a[0]; v[1]=a[1]; v[2]=a[2]; v[3]=a[3]; }
    { f32x4 a = *(const f32x4*)&sc[fr][fg*8 + 4];
      v[4]=a[0]; v[5]=a[1]; v[6]=a[2]; v[7]=a[3]; }
    { f32x4 a = *(const f32x4*)&sc[fr][32 + fg*8];
      v[8]=a[0]; v[9]=a[1]; v[10]=a[2]; v[11]=a[3]; }
    { f32x4 a = *(const f32x4*)&sc[fr][32 + fg*8 + 4];
      v[12]=a[0]; v[13]=a[1]; v[14]=a[2]; v[15]=a[3]; }
    // ---- online softmax (row fr; 4 replicas across fg) ----
    float mx = v[0];
    #pragma unroll
    for (int t = 1; t < 16; t++) mx = fmaxf(mx, v[t]);
    mx = fmaxf(mx, __shfl_xor(mx, 16));
    mx = fmaxf(mx, __shfl_xor(mx, 32));
    float mnew = fmaxf(m_run, mx);
    float fac = __expf(m_run - mnew);
    float p[16], ps = 0.f;
    #pragma unroll
    for (int t = 0; t < 16; t++){ p[t] = __expf(v[t] - mnew); ps += p[t]; }
    ps += __shfl_xor(ps, 16);
    ps += __shfl_xor(ps, 32);
    l_run = l_run * fac + ps;
    m_run = mnew;
    // ---- redistribute fac to accumulator rows (fg*4+r), rescale ----
    float f0 = __shfl(fac, fg*4 + 0);
    float f1 = __shfl(fac, fg*4 + 1);
    float f2 = __shfl(fac, fg*4 + 2);
    float f3 = __shfl(fac, fg*4 + 3);
    o0[0]*=f0; o0[1]*=f1; o0[2]*=f2; o0[3]*=f3;
    o1[0]*=f0; o1[1]*=f1; o1[2]*=f2; o1[3]*=f3;
    // ---- P -> bf16 (packed cvt), PV with pre-loaded vT ----
    union { u32 wd[4]; bf16x8 v8; } pa0u, pa1u;
    #pragma unroll
    for (int t = 0; t < 4; t++){
      pa0u.wd[t] = cvtpk(p[2*t], p[2*t+1]);
      pa1u.wd[t] = cvtpk(p[8 + 2*t], p[9 + 2*t]);
    }
    o0 = MFMA16(pa0u.v8, vf00, o0, 0, 0, 0);
    o0 = MFMA16(pa1u.v8, vf01, o0, 0, 0, 0);
    o1 = MFMA16(pa0u.v8, vf10, o1, 0, 0, 0);
    o1 = MFMA16(pa1u.v8, vf11, o1, 0, 0, 0);
    // ---- rotate prefetch buffers ----
    kf0 = nkf0; kf1 = nkf1; kf2 = nkf2; kf3 = nkf3;
    bk0 = nbk0; bk1 = nbk1; bk2 = nbk2; bk3 = nbk3;
  }

  // ---- write unnormalized partials ----
  float* ob = opart + (size_t)jc*NN*DM;
  #pragma unroll
  for (int r = 0; r < 4; r++){
    size_t row = i0 + fg*4 + r;
    ob[row*DM + h*HDIM + fr]      = o0[r];
    ob[row*DM + h*HDIM + 16 + fr] = o1[r];
  }
  if (fg == 0){
    mpart[jc*NN*NH + (i0 + fr)*NH + h] = m_run;
    lpart[jc*NN*NH + (i0 + fr)*NH + h] = l_run;
  }
}

// ---------------- combine J-split partials ----------------
__global__ __launch_bounds__(256)
void k_reduce(const float* __restrict__ opart, const float* __restrict__ mpart,
              const float* __restrict__ lpart, u16* __restrict__ aob){
  int row = blockIdx.x, col = threadIdx.x, h = col >> 5;
  float m[JSPLIT], l[JSPLIT];
  float M = -3.0e38f;
  #pragma unroll
  for (int jc = 0; jc < JSPLIT; jc++){
    m[jc] = mpart[jc*NN*NH + row*NH + h];
    l[jc] = lpart[jc*NN*NH + row*NH + h];
    M = fmaxf(M, m[jc]);
  }
  float L = 0.f, acc = 0.f;
  #pragma unroll
  for (int jc = 0; jc < JSPLIT; jc++){
    float w = __expf(m[jc] - M);
    L += l[jc] * w;
    acc += opart[(size_t)jc*NN*DM + (size_t)row*DM + col] * w;
  }
  aob[(size_t)row*DM + col] = f2bf(acc / L);
}

// ---------------- launcher ----------------
extern "C" void kernel_launch(void* const* d_in, const int* in_sizes, int n_in,
                              void* d_out, int out_size, void* d_ws, size_t ws_size,
                              hipStream_t stream){
  const float* x     = (const float*)d_in[0];
  const int*   ei    = (const int*)d_in[1];
  const int*   etyp  = (const int*)d_in[2];
  const float* pos   = (const float*)d_in[3];
  const float* ewin  = (const float*)d_in[4];
  const float* Wq    = (const float*)d_in[5];
  const float* bq    = (const float*)d_in[6];
  const float* Wk    = (const float*)d_in[7];
  const float* bk    = (const float*)d_in[8];
  const float* Wv    = (const float*)d_in[9];
  const float* bv    = (const float*)d_in[10];
  const float* Wo    = (const float*)d_in[11];
  const float* bo    = (const float*)d_in[12];
  const float* spd   = (const float*)d_in[13];
  const float* ett   = (const float*)d_in[14];
  const float* slb   = (const float*)d_in[15];
  const float* inde  = (const float*)d_in[16];
  const float* outde = (const float*)d_in[17];
  const float* dsc   = (const float*)d_in[18];
  const float* ln1g  = (const float*)d_in[19];
  const float* ln1b  = (const float*)d_in[20];
  const float* ln2g  = (const float*)d_in[21];
  const float* ln2b  = (const float*)d_in[22];
  const float* W1    = (const float*)d_in[23];
  const float* b1    = (const float*)d_in[24];
  const float* W2    = (const float*)d_in[25];
  const float* b2    = (const float*)d_in[26];
  const int* src = ei;
  const int* dst = ei + NE;

  char* p = (char*)d_ws;
  auto alloc = [&](size_t bytes) -> void* {
    void* r = (void*)p;
    p += (bytes + 255) & ~(size_t)255;
    return r;
  };
  // zeroed region (contiguous): deg_in, deg_out, bcnt, bfill
  int*  deg_in  = (int*)alloc(NN*4);
  int*  deg_out = (int*)alloc(NN*4);
  int*  bcnt    = (int*)alloc(9216*4);
  int*  bfill   = (int*)alloc(9216*4);
  int*  bptr    = (int*)alloc(9217*4);
  u16*  meta    = (u16*)alloc(NE*2);
  float* ews    = (float*)alloc(NE*4);
  unsigned char* bktP = (unsigned char*)alloc((size_t)NN*NN);
  float* xb     = (float*)alloc((size_t)NN*DM*4);
  float* x2     = (float*)alloc((size_t)NN*DM*4);
  u16*  xnb     = (u16*)alloc((size_t)NN*DM*2);
  u16*  x2nb    = (u16*)alloc((size_t)NN*DM*2);
  u16*  qb      = (u16*)alloc((size_t)NN*DM*2);   // qb, kb contiguous
  u16*  kb      = (u16*)alloc((size_t)NN*DM*2);
  u16*  vT      = (u16*)alloc((size_t)NN*DM*2);
  u16*  aob     = (u16*)alloc((size_t)NN*DM*2);
  u16*  h1b     = (u16*)alloc((size_t)NN*DFF*2);
  float* opart  = (float*)alloc((size_t)JSPLIT*NN*DM*4);
  float* mpart  = (float*)alloc((size_t)JSPLIT*NN*NH*4);
  float* lpart  = (float*)alloc((size_t)JSPLIT*NN*NH*4);
  u16*  Wqkvot  = (u16*)alloc(4*65536*2);          // Wq^T,Wk^T,Wv^T,Wo^T contiguous
  u16*  W1t     = (u16*)alloc(262144*2);
  u16*  W2t     = (u16*)alloc(262144*2);

  hipMemsetAsync(deg_in, 0, (2*NN + 2*9216)*4, stream);

  k_deg<<<NE/256, 256, 0, stream>>>(src, dst, deg_out, deg_in, bcnt);
  k_scan<<<1, 1024, 0, stream>>>(bcnt, bptr);
  k_scatter<<<NE/256, 256, 0, stream>>>(src, dst, etyp, ewin, bptr, bfill, meta, ews);
  k_bucket<<<dim3(3, NN), 1024, 0, stream>>>(pos, bktP);
  k_trans<<<768, 256, 0, stream>>>(Wq, Wk, Wv, Wo, W1, W2, Wqkvot, W1t, W2t);
  k_ln<<<NN, 256, 0, stream>>>(x, deg_in, deg_out, inde, outde, dsc, ln1g, ln1b, xb, xnb);

  // fused QKV: Bt = [Wq^T; Wk^T; Wv^T] (768 x 256)
  k_gemm<<<dim3(12, 48), 256, 0, stream>>>(xnb, Wqkvot, bq, bk, bv, nullptr,
                                           qb, vT, DM, 768, 5);

  k_attn<<<dim3(NIT, JSPLIT), 512, 0, stream>>>(qb, kb, vT, bktP, spd, slb, meta, ews,
                                                ett, bptr, opart, mpart, lpart);
  k_reduce<<<NN, 256, 0, stream>>>(opart, mpart, lpart, aob);

  u16* Wot = Wqkvot + 3*65536;
  k_gemm<<<dim3(4, 48), 256, 0, stream>>>(aob, Wot, bo, nullptr, nullptr, xb,
                                          x2, nullptr, DM, DM, 2);
  k_ln<<<NN, 256, 0, stream>>>(x2, nullptr, nullptr, nullptr, nullptr, nullptr,
                               ln2g, ln2b, nullptr, x2nb);
  k_gemm<<<dim3(16, 48), 256, 0, stream>>>(x2nb, W1t, b1, nullptr, nullptr, nullptr,
                                           h1b, nullptr, DM, DFF, 3);
  k_gemm<<<dim3(4, 48), 256, 0, stream>>>(h1b, W2t, b2, nullptr, nullptr, x2,
                                          d_out, nullptr, DFF, DM, 2);
}